// Round 2
// baseline (374.898 us; speedup 1.0000x reference)
//
#include <hip/hip_runtime.h>
#include <math.h>

// Problem shape (fixed by setup_inputs)
constexpr int Bn = 8, Dn = 64, Hn = 256, Wn = 512;
constexpr int HW   = Hn * Wn;             // 131072
constexpr int NPIX = Bn * HW;             // 1048576
constexpr int TPB  = 256;
constexpr int PPT  = 4;                   // pixels per thread (one float4)
constexpr int NBLK = NPIX / (TPB * PPT);  // 1024
constexpr int UF   = 8;                   // d-planes per pipeline stage
constexpr int NG   = Dn / UF;             // 8 stages

typedef float fx4 __attribute__((ext_vector_type(4)));

// entropy(p) = log(sum_d exp(sim_d)) - (sum_d T_d*sim_d)/(sum_d T_d),
// T_d = exp(-|gt - 2d|); Laplace 1/(2*DIVERSITY) cancels in the ratio.
__global__ __launch_bounds__(TPB) void sce_main(const float* __restrict__ sim,
                                                const float* __restrict__ gt,
                                                float* __restrict__ accf,
                                                unsigned* __restrict__ ticket,
                                                float* __restrict__ out) {
    const int tid = blockIdx.x * TPB + threadIdx.x;
    const int p0  = tid * PPT;
    const int b   = p0 / HW;
    const int rem = p0 - b * HW;
    const fx4* simv = reinterpret_cast<const fx4*>(sim + (size_t)b * Dn * HW + rem);
    const int ds = HW / 4;                // fx4 stride between d-planes

    const fx4 g4 = __builtin_nontemporal_load(reinterpret_cast<const fx4*>(gt + p0));
    float gg[4] = {g4.x, g4.y, g4.z, g4.w};

    float s[4]  = {0.f, 0.f, 0.f, 0.f};   // sum exp(sim)
    float S1[4] = {0.f, 0.f, 0.f, 0.f};   // sum T
    float S2[4] = {0.f, 0.f, 0.f, 0.f};   // sum T*sim

    // Software pipeline: keep the next 8 plane-loads in flight during compute.
    fx4 cur[UF], nxt[UF];
#pragma unroll
    for (int i = 0; i < UF; ++i)
        cur[i] = __builtin_nontemporal_load(&simv[(size_t)i * ds]);

#pragma unroll
    for (int g = 0; g < NG; ++g) {
        if (g + 1 < NG) {
#pragma unroll
            for (int i = 0; i < UF; ++i)
                nxt[i] = __builtin_nontemporal_load(&simv[(size_t)((g + 1) * UF + i) * ds]);
        }
#pragma unroll
        for (int i = 0; i < UF; ++i) {
            const float dd = 2.0f * (float)(g * UF + i);
            float v[4] = {cur[i].x, cur[i].y, cur[i].z, cur[i].w};
#pragma unroll
            for (int j = 0; j < 4; ++j) {
                s[j] += __expf(v[j]);
                float t = __expf(-fabsf(gg[j] - dd));
                S1[j] += t;
                S2[j] = fmaf(t, v[j], S2[j]);
            }
        }
#pragma unroll
        for (int i = 0; i < UF; ++i) cur[i] = nxt[i];
    }

    float lsum = 0.0f, lcnt = 0.0f;
#pragma unroll
    for (int j = 0; j < 4; ++j) {
        if (isfinite(gg[j])) {            // unknown gt = inf -> excluded
            lsum += __logf(s[j]) - S2[j] / S1[j];
            lcnt += 1.0f;
        }
    }

    // 64-lane wave reduction
#pragma unroll
    for (int off = 32; off > 0; off >>= 1) {
        lsum += __shfl_down(lsum, off, 64);
        lcnt += __shfl_down(lcnt, off, 64);
    }

    __shared__ float ssum[TPB / 64], scnt[TPB / 64];
    const int lane = threadIdx.x & 63;
    const int wave = threadIdx.x >> 6;
    if (lane == 0) { ssum[wave] = lsum; scnt[wave] = lcnt; }
    __syncthreads();
    if (threadIdx.x == 0) {
        float bs = 0.f, bc = 0.f;
#pragma unroll
        for (int w = 0; w < TPB / 64; ++w) { bs += ssum[w]; bc += scnt[w]; }
        atomicAdd(&accf[0], bs);          // device-scope by default
        atomicAdd(&accf[1], bc);
        __threadfence();                  // release our sums before ticket
        unsigned old = atomicAdd(ticket, 1u);
        if (old == NBLK - 1) {            // last block finalizes (saves a launch)
            __threadfence();
            float ts = atomicAdd(&accf[0], 0.0f);  // coherent RMW read
            float tc = atomicAdd(&accf[1], 0.0f);
            out[0] = ts / tc;
        }
    }
}

extern "C" void kernel_launch(void* const* d_in, const int* in_sizes, int n_in,
                              void* d_out, int out_size, void* d_ws, size_t ws_size,
                              hipStream_t stream) {
    const float* sim = (const float*)d_in[0];
    const float* gt  = (const float*)d_in[1];
    float* accf = (float*)d_ws;                         // [sum, cnt]
    unsigned* ticket = (unsigned*)d_ws + 2;             // block-done counter
    hipMemsetAsync(d_ws, 0, 16, stream);                // ws re-poisoned 0xAA each call
    sce_main<<<NBLK, TPB, 0, stream>>>(sim, gt, accf, ticket, (float*)d_out);
}